// Round 15
// baseline (55.931 us; speedup 1.0000x reference)
//
#include <hip/hip_runtime.h>
#include <stdint.h>

#define H 128
#define W 128
#define CIN 64
#define COUT 64
#define NB 8
#define WR 8        // pixel rows per block (4 waves x 2 rows)
#define WC 16       // pixel cols per block
#define CW 20       // staged cols per window row (WC+4)
#define NR 12       // staged rows (WR+4)
#define PLANE 242   // slots per chunk-plane; 242 % 8 == 2 -> quarter decorrelation

typedef __attribute__((ext_vector_type(4))) float f32x4;
typedef __attribute__((ext_vector_type(2))) _Float16 f16x2;
typedef __attribute__((ext_vector_type(8))) _Float16 f16x8;
typedef __attribute__((ext_vector_type(4))) unsigned int u32x4;
typedef __attribute__((ext_vector_type(2))) unsigned int u32x2;

__device__ __forceinline__ f16x2 bch2(unsigned u) { return __builtin_bit_cast(f16x2, u); }
__device__ __forceinline__ unsigned bcu(f16x2 v) { return __builtin_bit_cast(unsigned, v); }

// ---- kernel 0: x NCHW f32 -> NHWC f16 (xt[b][h][w][c]) via LDS tile transpose
__global__ __launch_bounds__(256) void x_to_nhwc(const float* __restrict__ x,
                                                 _Float16* __restrict__ xt) {
    __shared__ _Float16 tile[W][68];
    int bh = blockIdx.x;
    int h = bh & (H - 1), b = bh >> 7;
    int t = threadIdx.x;
    #pragma unroll
    for (int i = 0; i < 8; ++i) {
        int idx = i * 256 + t;
        int c = idx >> 5;
        int w4 = (idx & 31) << 2;
        f32x4 v = *(const f32x4*)(x + (((size_t)(b * CIN + c) * H + h) * W + w4));
        #pragma unroll
        for (int j = 0; j < 4; ++j) tile[w4 + j][c] = (_Float16)v[j];
    }
    __syncthreads();
    _Float16* dst = xt + (size_t)bh * W * CIN;
    #pragma unroll
    for (int i = 0; i < 8; ++i) {
        int idx = i * 256 + t;
        int w = idx >> 4;
        int c4 = (idx & 15) << 2;
        *(uint2*)(dst + (size_t)w * CIN + c4) = *(const uint2*)&tile[w][c4];
    }
}

// ---- kernel 1: prepack weights, MFMA-lane-coalesced layout
//  wao2[((kk*2+m)*64 + l)*8 + j] ; wac2[((kk*4+m)*64 + l)*8 + j]
//  element = w[cout = m*16+(l&15)][cin = (kk&1)*32 + (l>>4)*8 + j][tap = kk>>1]
__global__ __launch_bounds__(256) void prep_w(const float* __restrict__ wo,
                                              const float* __restrict__ wc,
                                              _Float16* __restrict__ wao2,
                                              _Float16* __restrict__ wac2) {
    int t = blockIdx.x * 256 + threadIdx.x;
    if (t < 18432) {
        int j = t & 7, l = (t >> 3) & 63, m = (t >> 9) & 1, kk = t >> 10;
        int cout = m * 16 + (l & 15);
        int cin = (kk & 1) * 32 + ((l >> 4) << 3) + j;
        wao2[t] = (cout < 18) ? (_Float16)wo[(cout * 64 + cin) * 9 + (kk >> 1)]
                              : (_Float16)0.f;
    } else if (t < 18432 + 36864) {
        int u = t - 18432;
        int j = u & 7, l = (u >> 3) & 63, m = (u >> 9) & 3, kk = u >> 11;
        int cout = m * 16 + (l & 15);
        int cin = (kk & 1) * 32 + ((l >> 4) << 3) + j;
        wac2[u] = (_Float16)wc[(cout * 64 + cin) * 9 + (kk >> 1)];
    }
}

// ---- kernel 2: fused offset-conv + coord setup + deformable conv.
// 4 waves x 2 FULL rows each (no K-split): no partial reductions, direct
// global writes. Meta goes through s_meta LDS (proven R5-R13 pattern).
// TWO barriers total: after staging, after setup.
__global__ __launch_bounds__(256, 3) void deform_fused(const _Float16* __restrict__ xt,
                                                       const _Float16* __restrict__ wao2,
                                                       const _Float16* __restrict__ wac2,
                                                       const float* __restrict__ bo,
                                                       const float* __restrict__ bconv,
                                                       float* __restrict__ out) {
    __shared__ u32x4 s_x[8 * PLANE];     // 31.0 KB chunk-planes
    __shared__ float s_meta[8][432];     // per pixel-row: aw[144] | wq pairs[288]

    int bid = blockIdx.x;
    int b = bid & 7;                      // XCD swizzle: XCD k <- batch k
    int r = bid >> 3;                     // 0..127
    int h0 = ((r >> 3) & 15) << 3;
    int w0 = (r & 7) << 4;
    int vy = h0 - 2, vx = w0 - 2;         // window origin (12 rows x 20 cols)

    int t = threadIdx.x;
    int lane = t & 63, wv = t >> 6;
    int pcol = lane & 15, hq = lane >> 4;
    int r0 = h0 + 2 * wv, r1 = r0 + 1;    // this wave's two rows
    int wp = w0 + pcol;

    const _Float16* xb = xt + (size_t)b * H * W * CIN;

    // ---------- stage x window (clamp-uniform) ----------
    for (int i = t; i < NR * CW * 8; i += 256) {
        int ch = i & 7;
        int q2 = i >> 3;
        int rr = q2 / CW;
        int cs = q2 - rr * CW;
        int row = min(max(vy + rr, 0), H - 1);
        int col = min(max(vx + cs, 0), W - 1);
        s_x[ch * PLANE + rr * CW + cs] =
            *(const u32x4*)(xb + (size_t)(row * W + col) * CIN + (ch << 3));
    }
    __syncthreads();                      // barrier 1

    // ---------- phase A: full 64-ch offset conv, 2 rows (R5 pattern x2) ----------
    f32x4 aA0 = {}, aA1 = {}, aB0 = {}, aB1 = {};
    #pragma unroll
    for (int k = 0; k < 9; ++k) {
        int ky = k / 3 - 1, kx = k % 3 - 1;
        int xx = wp + kx;
        bool vxok = (unsigned)xx < (unsigned)W;
        int xc = min(max(xx, 0), W - 1) - vx;
        int yyA = r0 + ky, yyB = r1 + ky;
        int sA = (min(max(yyA, 0), H - 1) - vy) * CW + xc;
        int sB = (min(max(yyB, 0), H - 1) - vy) * CW + xc;
        u32x4 veA = s_x[hq * PLANE + sA], voA = s_x[(4 + hq) * PLANE + sA];
        u32x4 veB = s_x[hq * PLANE + sB], voB = s_x[(4 + hq) * PLANE + sB];
        u32x4 z = {};
        if (!(vxok && (unsigned)yyA < (unsigned)H)) { veA = z; voA = z; }
        if (!(vxok && (unsigned)yyB < (unsigned)H)) { veB = z; voB = z; }
        f16x8 beA = __builtin_bit_cast(f16x8, veA);
        f16x8 boA = __builtin_bit_cast(f16x8, voA);
        f16x8 beB = __builtin_bit_cast(f16x8, veB);
        f16x8 boB = __builtin_bit_cast(f16x8, voB);
        const _Float16* wb = wao2 + (size_t)(4 * k) * 512 + lane * 8;
        f16x8 wf0 = *(const f16x8*)(wb);
        f16x8 wf1 = *(const f16x8*)(wb + 512);
        f16x8 wf2 = *(const f16x8*)(wb + 1024);
        f16x8 wf3 = *(const f16x8*)(wb + 1536);
        aA0 = __builtin_amdgcn_mfma_f32_16x16x32_f16(wf0, beA, aA0, 0, 0, 0);
        aA1 = __builtin_amdgcn_mfma_f32_16x16x32_f16(wf1, beA, aA1, 0, 0, 0);
        aA0 = __builtin_amdgcn_mfma_f32_16x16x32_f16(wf2, boA, aA0, 0, 0, 0);
        aA1 = __builtin_amdgcn_mfma_f32_16x16x32_f16(wf3, boA, aA1, 0, 0, 0);
        aB0 = __builtin_amdgcn_mfma_f32_16x16x32_f16(wf0, beB, aB0, 0, 0, 0);
        aB1 = __builtin_amdgcn_mfma_f32_16x16x32_f16(wf1, beB, aB1, 0, 0, 0);
        aB0 = __builtin_amdgcn_mfma_f32_16x16x32_f16(wf2, boB, aB0, 0, 0, 0);
        aB1 = __builtin_amdgcn_mfma_f32_16x16x32_f16(wf3, boB, aB1, 0, 0, 0);
    }

    // ---------- per-lane coordinate setup -> s_meta (R13 pattern) ----------
    {
        auto setup = [&](float* mrow, int row, int k, float dy, float dx) {
            float py = (float)(row + k / 3 - 1) + dy;
            float px = (float)(wp + k % 3 - 1) + dx;
            float y0f = floorf(py), x0f = floorf(px);
            float fy = py - y0f, fx = px - x0f;
            float vy0 = (y0f >= 0.f  && y0f <= 127.f) ? 1.f : 0.f;
            float vy1 = (y0f >= -1.f && y0f <= 126.f) ? 1.f : 0.f;
            float vx0 = (x0f >= 0.f  && x0f <= 127.f) ? 1.f : 0.f;
            float vx1 = (x0f >= -1.f && x0f <= 126.f) ? 1.f : 0.f;
            float g0 = (1.f - fy) * (1.f - fx) * vy0 * vx0;
            float g1 = (1.f - fy) * fx         * vy0 * vx1;
            float g2 = fy * (1.f - fx)         * vy1 * vx0;
            float g3 = fy * fx                 * vy1 * vx1;
            int y0i = (int)fminf(fmaxf(y0f, 0.f), 127.f);
            int x0i = (int)fminf(fmaxf(x0f, 0.f), 127.f);
            int y1i = (int)fminf(fmaxf(y0f + 1.f, 0.f), 127.f);
            int x1i = (int)fminf(fmaxf(x0f + 1.f, 0.f), 127.f);
            unsigned dxb = (unsigned)(x1i - x0i);
            unsigned dyb = (unsigned)(y1i - y0i);
            bool inw = (y0i >= vy) && (y1i <= vy + NR - 1) &&
                       (x0i >= vx) && (x1i <= vx + CW - 1);
            unsigned s00 = inw ? (unsigned)((y0i - vy) * CW + (x0i - vx)) : 0u;
            unsigned a00 = (unsigned)(y0i * W + x0i);
            unsigned awv = s00 | (dxb << 9) | (dyb << 10) | (inw ? 0u : (1u << 11)) | (a00 << 12);
            int idx = k * 16 + pcol;
            ((unsigned*)mrow)[idx] = awv;
            ((unsigned*)mrow)[144 + 2 * idx]     = bcu((f16x2){(_Float16)g0, (_Float16)g1});
            ((unsigned*)mrow)[144 + 2 * idx + 1] = bcu((f16x2){(_Float16)g2, (_Float16)g3});
        };
        f32x4 bo4 = *(const f32x4*)(bo + 4 * hq);
        setup(s_meta[2 * wv],     r0, 2 * hq,     aA0[0] + bo4[0], aA0[1] + bo4[1]);
        setup(s_meta[2 * wv],     r0, 2 * hq + 1, aA0[2] + bo4[2], aA0[3] + bo4[3]);
        setup(s_meta[2 * wv + 1], r1, 2 * hq,     aB0[0] + bo4[0], aB0[1] + bo4[1]);
        setup(s_meta[2 * wv + 1], r1, 2 * hq + 1, aB0[2] + bo4[2], aB0[3] + bo4[3]);
        if (hq == 0) {
            setup(s_meta[2 * wv],     r0, 8, aA1[0] + bo[16], aA1[1] + bo[17]);
            setup(s_meta[2 * wv + 1], r1, 8, aB1[0] + bo[16], aB1[1] + bo[17]);
        }
    }
    __syncthreads();                      // barrier 2

    // ---------- phase C: deformable conv, 2 rows, full 64 ch (R5 pattern x2) ----
    const _Float16* xh = xb + (hq << 3);
    const u32x4* se = s_x + hq * PLANE;
    const u32x4* so = s_x + (4 + hq) * PLANE;
    const unsigned* mA = (const unsigned*)s_meta[2 * wv];
    const unsigned* mB = (const unsigned*)s_meta[2 * wv + 1];
    f32x4 accA[4] = {}, accB[4] = {};

    #pragma unroll
    for (int k = 0; k < 9; ++k) {
        int idx = k * 16 + pcol;
        unsigned awA = mA[idx];
        unsigned awB = mB[idx];
        u32x2 wqA = *(const u32x2*)&mA[144 + 2 * idx];
        u32x2 wqB = *(const u32x2*)&mB[144 + 2 * idx];

        const _Float16* ab = wac2 + (size_t)(8 * k) * 512 + lane * 8;
        f16x8 wm0 = *(const f16x8*)(ab);
        f16x8 wm1 = *(const f16x8*)(ab + 512);
        f16x8 wm2 = *(const f16x8*)(ab + 1024);
        f16x8 wm3 = *(const f16x8*)(ab + 1536);
        f16x8 wn0 = *(const f16x8*)(ab + 2048);
        f16x8 wn1 = *(const f16x8*)(ab + 2560);
        f16x8 wn2 = *(const f16x8*)(ab + 3072);
        f16x8 wn3 = *(const f16x8*)(ab + 3584);

        // ---- row A ----
        {
            unsigned sA = awA & 511u, dxA = (awA >> 9) & 1u, dyA = (awA >> 10) & 1u;
            u32x4 e00 = se[sA], e01 = se[sA + dxA];
            u32x4 e10 = se[sA + dyA * CW], e11 = se[sA + dyA * CW + dxA];
            u32x4 o00 = so[sA], o01 = so[sA + dxA];
            u32x4 o10 = so[sA + dyA * CW], o11 = so[sA + dyA * CW + dxA];
            if (__builtin_expect((awA & (1u << 11)) != 0u, 0)) {
                unsigned a0_ = awA >> 12;
                const _Float16* p00 = xh + (size_t)a0_ * CIN;
                const _Float16* p01 = xh + (size_t)(a0_ + dxA) * CIN;
                const _Float16* p10 = xh + (size_t)(a0_ + (dyA << 7)) * CIN;
                const _Float16* p11 = xh + (size_t)(a0_ + (dyA << 7) + dxA) * CIN;
                e00 = *(const u32x4*)p00; o00 = *(const u32x4*)(p00 + 32);
                e01 = *(const u32x4*)p01; o01 = *(const u32x4*)(p01 + 32);
                e10 = *(const u32x4*)p10; o10 = *(const u32x4*)(p10 + 32);
                e11 = *(const u32x4*)p11; o11 = *(const u32x4*)(p11 + 32);
            }
            f16x2 wab = bch2(wqA[0]), wcd = bch2(wqA[1]);
            f16x2 w00d = (f16x2){wab[0], wab[0]}, w01d = (f16x2){wab[1], wab[1]};
            f16x2 w10d = (f16x2){wcd[0], wcd[0]}, w11d = (f16x2){wcd[1], wcd[1]};
            u32x4 fe, fo;
            #pragma unroll
            for (int d = 0; d < 4; ++d) {
                f16x2 ve = bch2(e00[d]) * w00d + bch2(e01[d]) * w01d
                         + bch2(e10[d]) * w10d + bch2(e11[d]) * w11d;
                f16x2 vo = bch2(o00[d]) * w00d + bch2(o01[d]) * w01d
                         + bch2(o10[d]) * w10d + bch2(o11[d]) * w11d;
                fe[d] = bcu(ve);
                fo[d] = bcu(vo);
            }
            f16x8 bfe = __builtin_bit_cast(f16x8, fe);
            f16x8 bfo = __builtin_bit_cast(f16x8, fo);
            accA[0] = __builtin_amdgcn_mfma_f32_16x16x32_f16(wm0, bfe, accA[0], 0, 0, 0);
            accA[1] = __builtin_amdgcn_mfma_f32_16x16x32_f16(wm1, bfe, accA[1], 0, 0, 0);
            accA[2] = __builtin_amdgcn_mfma_f32_16x16x32_f16(wm2, bfe, accA[2], 0, 0, 0);
            accA[3] = __builtin_amdgcn_mfma_f32_16x16x32_f16(wm3, bfe, accA[3], 0, 0, 0);
            accA[0] = __builtin_amdgcn_mfma_f32_16x16x32_f16(wn0, bfo, accA[0], 0, 0, 0);
            accA[1] = __builtin_amdgcn_mfma_f32_16x16x32_f16(wn1, bfo, accA[1], 0, 0, 0);
            accA[2] = __builtin_amdgcn_mfma_f32_16x16x32_f16(wn2, bfo, accA[2], 0, 0, 0);
            accA[3] = __builtin_amdgcn_mfma_f32_16x16x32_f16(wn3, bfo, accA[3], 0, 0, 0);
        }
        // ---- row B ----
        {
            unsigned sB = awB & 511u, dxB = (awB >> 9) & 1u, dyB = (awB >> 10) & 1u;
            u32x4 e00 = se[sB], e01 = se[sB + dxB];
            u32x4 e10 = se[sB + dyB * CW], e11 = se[sB + dyB * CW + dxB];
            u32x4 o00 = so[sB], o01 = so[sB + dxB];
            u32x4 o10 = so[sB + dyB * CW], o11 = so[sB + dyB * CW + dxB];
            if (__builtin_expect((awB & (1u << 11)) != 0u, 0)) {
                unsigned b0_ = awB >> 12;
                const _Float16* p00 = xh + (size_t)b0_ * CIN;
                const _Float16* p01 = xh + (size_t)(b0_ + dxB) * CIN;
                const _Float16* p10 = xh + (size_t)(b0_ + (dyB << 7)) * CIN;
                const _Float16* p11 = xh + (size_t)(b0_ + (dyB << 7) + dxB) * CIN;
                e00 = *(const u32x4*)p00; o00 = *(const u32x4*)(p00 + 32);
                e01 = *(const u32x4*)p01; o01 = *(const u32x4*)(p01 + 32);
                e10 = *(const u32x4*)p10; o10 = *(const u32x4*)(p10 + 32);
                e11 = *(const u32x4*)p11; o11 = *(const u32x4*)(p11 + 32);
            }
            f16x2 wab = bch2(wqB[0]), wcd = bch2(wqB[1]);
            f16x2 w00d = (f16x2){wab[0], wab[0]}, w01d = (f16x2){wab[1], wab[1]};
            f16x2 w10d = (f16x2){wcd[0], wcd[0]}, w11d = (f16x2){wcd[1], wcd[1]};
            u32x4 fe, fo;
            #pragma unroll
            for (int d = 0; d < 4; ++d) {
                f16x2 ve = bch2(e00[d]) * w00d + bch2(e01[d]) * w01d
                         + bch2(e10[d]) * w10d + bch2(e11[d]) * w11d;
                f16x2 vo = bch2(o00[d]) * w00d + bch2(o01[d]) * w01d
                         + bch2(o10[d]) * w10d + bch2(o11[d]) * w11d;
                fe[d] = bcu(ve);
                fo[d] = bcu(vo);
            }
            f16x8 bfe = __builtin_bit_cast(f16x8, fe);
            f16x8 bfo = __builtin_bit_cast(f16x8, fo);
            accB[0] = __builtin_amdgcn_mfma_f32_16x16x32_f16(wm0, bfe, accB[0], 0, 0, 0);
            accB[1] = __builtin_amdgcn_mfma_f32_16x16x32_f16(wm1, bfe, accB[1], 0, 0, 0);
            accB[2] = __builtin_amdgcn_mfma_f32_16x16x32_f16(wm2, bfe, accB[2], 0, 0, 0);
            accB[3] = __builtin_amdgcn_mfma_f32_16x16x32_f16(wm3, bfe, accB[3], 0, 0, 0);
            accB[0] = __builtin_amdgcn_mfma_f32_16x16x32_f16(wn0, bfo, accB[0], 0, 0, 0);
            accB[1] = __builtin_amdgcn_mfma_f32_16x16x32_f16(wn1, bfo, accB[1], 0, 0, 0);
            accB[2] = __builtin_amdgcn_mfma_f32_16x16x32_f16(wn2, bfo, accB[2], 0, 0, 0);
            accB[3] = __builtin_amdgcn_mfma_f32_16x16x32_f16(wn3, bfo, accB[3], 0, 0, 0);
        }
    }

    // ---------- direct output (complete sums in registers) ----------
    #pragma unroll
    for (int m = 0; m < 4; ++m) {
        f32x4 bc4 = *(const f32x4*)(bconv + m * 16 + (hq << 2));
        #pragma unroll
        for (int j = 0; j < 4; ++j) {
            int co = (m << 4) + (hq << 2) + j;
            out[(((size_t)b * COUT + co) * H + r0) * W + wp] = accA[m][j] + bc4[j];
            out[(((size_t)b * COUT + co) * H + r1) * W + wp] = accB[m][j] + bc4[j];
        }
    }
}

extern "C" void kernel_launch(void* const* d_in, const int* in_sizes, int n_in,
                              void* d_out, int out_size, void* d_ws, size_t ws_size,
                              hipStream_t stream) {
    const float* x  = (const float*)d_in[0];
    const float* wo = (const float*)d_in[1];
    const float* bo = (const float*)d_in[2];
    const float* wc = (const float*)d_in[3];
    const float* bc = (const float*)d_in[4];
    float* out = (float*)d_out;

    _Float16* xt   = (_Float16*)d_ws;                                   // 16.78 MB
    _Float16* wao2 = (_Float16*)((char*)d_ws + (size_t)NB * H * W * CIN * 2);
    _Float16* wac2 = wao2 + 18432;

    x_to_nhwc<<<NB * H, 256, 0, stream>>>(x, xt);
    prep_w<<<(18432 + 36864 + 255) / 256, 256, 0, stream>>>(wo, wc, wao2, wac2);
    deform_fused<<<NB * H * W / (WR * WC), 256, 0, stream>>>(xt, wao2, wac2, bo, bc, out);
}

// Round 16
// 50.750 us; speedup vs baseline: 1.1021x; 1.1021x over previous
//
#include <hip/hip_runtime.h>
#include <stdint.h>

#define H 128
#define W 128
#define CIN 64
#define COUT 64
#define NB 8
#define WR 4        // pixel rows per block
#define WC 16       // pixel cols per block
#define CW 20       // staged cols per window row (WC+4)
#define NR 8        // staged rows (WR+4)
#define PLANE 162   // slots per chunk-plane; 162 % 8 == 2 -> quarter decorrelation
#define REDS 260    // reduction scratch row stride (floats)

typedef __attribute__((ext_vector_type(4))) float f32x4;
typedef __attribute__((ext_vector_type(2))) _Float16 f16x2;
typedef __attribute__((ext_vector_type(8))) _Float16 f16x8;
typedef __attribute__((ext_vector_type(4))) unsigned int u32x4;
typedef __attribute__((ext_vector_type(2))) unsigned int u32x2;

__device__ __forceinline__ f16x2 bch2(unsigned u) { return __builtin_bit_cast(f16x2, u); }
__device__ __forceinline__ unsigned bcu(f16x2 v) { return __builtin_bit_cast(unsigned, v); }

// ---- kernel 0: x NCHW f32 -> NHWC f16 (xt[b][h][w][c]) via LDS tile transpose
__global__ __launch_bounds__(256) void x_to_nhwc(const float* __restrict__ x,
                                                 _Float16* __restrict__ xt) {
    __shared__ _Float16 tile[W][68];
    int bh = blockIdx.x;
    int h = bh & (H - 1), b = bh >> 7;
    int t = threadIdx.x;
    #pragma unroll
    for (int i = 0; i < 8; ++i) {
        int idx = i * 256 + t;
        int c = idx >> 5;
        int w4 = (idx & 31) << 2;
        f32x4 v = *(const f32x4*)(x + (((size_t)(b * CIN + c) * H + h) * W + w4));
        #pragma unroll
        for (int j = 0; j < 4; ++j) tile[w4 + j][c] = (_Float16)v[j];
    }
    __syncthreads();
    _Float16* dst = xt + (size_t)bh * W * CIN;
    #pragma unroll
    for (int i = 0; i < 8; ++i) {
        int idx = i * 256 + t;
        int w = idx >> 4;
        int c4 = (idx & 15) << 2;
        *(uint2*)(dst + (size_t)w * CIN + c4) = *(const uint2*)&tile[w][c4];
    }
}

// ---- kernel 1: prepack weights, MFMA-lane-coalesced layout
__global__ __launch_bounds__(256) void prep_w(const float* __restrict__ wo,
                                              const float* __restrict__ wc,
                                              _Float16* __restrict__ wao2,
                                              _Float16* __restrict__ wac2) {
    int t = blockIdx.x * 256 + threadIdx.x;
    if (t < 18432) {
        int j = t & 7, l = (t >> 3) & 63, m = (t >> 9) & 1, kk = t >> 10;
        int cout = m * 16 + (l & 15);
        int cin = (kk & 1) * 32 + ((l >> 4) << 3) + j;
        wao2[t] = (cout < 18) ? (_Float16)wo[(cout * 64 + cin) * 9 + (kk >> 1)]
                              : (_Float16)0.f;
    } else if (t < 18432 + 36864) {
        int u = t - 18432;
        int j = u & 7, l = (u >> 3) & 63, m = (u >> 9) & 3, kk = u >> 11;
        int cout = m * 16 + (l & 15);
        int cin = (kk & 1) * 32 + ((l >> 4) << 3) + j;
        wac2[u] = (_Float16)wc[(cout * 64 + cin) * 9 + (kk >> 1)];
    }
}

// ---- kernel 2: fused offset-conv + coord setup + deformable conv.
// R13 structure (proven 41us): 256 thr = 4 waves, wv = half*2 + q;
// K-split (half) x row-pair (q), 2 independent row-chains per wave.
// R16 tweaks: AW preloaded to regs; setprio around MFMA; merged epilogue.
__global__ __launch_bounds__(256, 4) void deform_fused(const _Float16* __restrict__ xt,
                                                       const _Float16* __restrict__ wao2,
                                                       const _Float16* __restrict__ wac2,
                                                       const float* __restrict__ bo,
                                                       const float* __restrict__ bconv,
                                                       float* __restrict__ out) {
    __shared__ u32x4 s_x[8 * PLANE];     // 20.7 KB chunk-planes
    __shared__ float s_meta[4][432];     // per pixel-row: aw[144] | wq pairs[288]

    int bid = blockIdx.x;
    int b = bid & 7;                      // XCD swizzle: XCD k <- batch k
    int r = bid >> 3;                     // 0..255
    int h0 = ((r >> 3) & 31) << 2;
    int w0 = (r & 7) << 4;
    int vy = h0 - 2, vx = w0 - 2;         // virtual window origin

    int t = threadIdx.x;
    int lane = t & 63, wv = t >> 6;
    int q = wv & 1;                       // row-pair index
    int half = wv >> 1;                   // 0: ch 0..31, 1: ch 32..63
    int pcol = lane & 15, hq = lane >> 4;
    int pl = half * 4 + hq;               // this lane's channel chunk (8 ch)
    int r0 = h0 + 2 * q, r1 = r0 + 1;
    int wp = w0 + pcol;

    const _Float16* xb = xt + (size_t)b * H * W * CIN;

    // ---------- stage x window (clamp-uniform, all 256 threads) ----------
    for (int i = t; i < NR * CW * 8; i += 256) {
        int ch = i & 7;
        int q2 = i >> 3;
        int rr = q2 / CW;
        int cs = q2 - rr * CW;
        int row = min(max(vy + rr, 0), H - 1);
        int col = min(max(vx + cs, 0), W - 1);
        s_x[ch * PLANE + rr * CW + cs] =
            *(const u32x4*)(xb + (size_t)(row * W + col) * CIN + (ch << 3));
    }
    __syncthreads();                      // barrier 1

    const u32x4* sp = s_x + pl * PLANE;

    // ---------- phase A: offset conv via MFMA, 2 rows per wave ----------
    f32x4 aA0 = {}, aA1 = {}, aB0 = {}, aB1 = {};
    #pragma unroll
    for (int k = 0; k < 9; ++k) {
        int ky = k / 3 - 1, kx = k % 3 - 1;
        int xx = wp + kx;
        bool vx_ok = (unsigned)xx < (unsigned)W;
        int xc = min(max(xx, 0), W - 1) - vx;
        int yyA = r0 + ky, yyB = r1 + ky;
        int sA = (min(max(yyA, 0), H - 1) - vy) * CW + xc;
        int sB = (min(max(yyB, 0), H - 1) - vy) * CW + xc;
        u32x4 vA = sp[sA], vB = sp[sB];
        u32x4 z = {};
        if (!(vx_ok && (unsigned)yyA < (unsigned)H)) vA = z;
        if (!(vx_ok && (unsigned)yyB < (unsigned)H)) vB = z;
        f16x8 bfA = __builtin_bit_cast(f16x8, vA);
        f16x8 bfB = __builtin_bit_cast(f16x8, vB);
        const _Float16* wb = wao2 + (size_t)(4 * k + 2 * half) * 512 + lane * 8;
        f16x8 a0 = *(const f16x8*)(wb);
        f16x8 a1 = *(const f16x8*)(wb + 512);
        aA0 = __builtin_amdgcn_mfma_f32_16x16x32_f16(a0, bfA, aA0, 0, 0, 0);
        aA1 = __builtin_amdgcn_mfma_f32_16x16x32_f16(a1, bfA, aA1, 0, 0, 0);
        aB0 = __builtin_amdgcn_mfma_f32_16x16x32_f16(a0, bfB, aB0, 0, 0, 0);
        aB1 = __builtin_amdgcn_mfma_f32_16x16x32_f16(a1, bfB, aB1, 0, 0, 0);
    }

    // ---------- reduce phase-A partials (half 1 -> LDS -> half 0) ----------
    if (half == 1) {
        float* scA = s_meta[2 * q] + lane * 6;
        scA[0] = aA0[0]; scA[1] = aA0[1]; scA[2] = aA0[2]; scA[3] = aA0[3];
        scA[4] = aA1[0]; scA[5] = aA1[1];
        float* scB = s_meta[2 * q + 1] + lane * 6;
        scB[0] = aB0[0]; scB[1] = aB0[1]; scB[2] = aB0[2]; scB[3] = aB0[3];
        scB[4] = aB1[0]; scB[5] = aB1[1];
    }
    __syncthreads();                      // barrier 2

    if (half == 0) {
        const float* scA = s_meta[2 * q] + lane * 6;
        const float* scB = s_meta[2 * q + 1] + lane * 6;
        float pA[6], pB[6];
        #pragma unroll
        for (int i = 0; i < 6; ++i) { pA[i] = scA[i]; pB[i] = scB[i]; }
        aA0[0] += pA[0]; aA0[1] += pA[1]; aA0[2] += pA[2]; aA0[3] += pA[3];
        aA1[0] += pA[4]; aA1[1] += pA[5];
        aB0[0] += pB[0]; aB0[1] += pB[1]; aB0[2] += pB[2]; aB0[3] += pB[3];
        aB1[0] += pB[4]; aB1[1] += pB[5];

        auto setup = [&](float* mrow, int row, int k, float dy, float dx) {
            float py = (float)(row + k / 3 - 1) + dy;
            float px = (float)(wp + k % 3 - 1) + dx;
            float y0f = floorf(py), x0f = floorf(px);
            float fy = py - y0f, fx = px - x0f;
            float vy0 = (y0f >= 0.f  && y0f <= 127.f) ? 1.f : 0.f;
            float vy1 = (y0f >= -1.f && y0f <= 126.f) ? 1.f : 0.f;
            float vx0 = (x0f >= 0.f  && x0f <= 127.f) ? 1.f : 0.f;
            float vx1 = (x0f >= -1.f && x0f <= 126.f) ? 1.f : 0.f;
            float g0 = (1.f - fy) * (1.f - fx) * vy0 * vx0;
            float g1 = (1.f - fy) * fx         * vy0 * vx1;
            float g2 = fy * (1.f - fx)         * vy1 * vx0;
            float g3 = fy * fx                 * vy1 * vx1;
            int y0i = (int)fminf(fmaxf(y0f, 0.f), 127.f);
            int x0i = (int)fminf(fmaxf(x0f, 0.f), 127.f);
            int y1i = (int)fminf(fmaxf(y0f + 1.f, 0.f), 127.f);
            int x1i = (int)fminf(fmaxf(x0f + 1.f, 0.f), 127.f);
            unsigned dxb = (unsigned)(x1i - x0i);
            unsigned dyb = (unsigned)(y1i - y0i);
            bool inw = (y0i >= vy) && (y1i <= vy + NR - 1) &&
                       (x0i >= vx) && (x1i <= vx + CW - 1);
            unsigned s00 = inw ? (unsigned)((y0i - vy) * CW + (x0i - vx)) : 0u;
            unsigned a00 = (unsigned)(y0i * W + x0i);
            unsigned awv = s00 | (dxb << 9) | (dyb << 10) | (inw ? 0u : (1u << 11)) | (a00 << 12);
            int idx = k * 16 + pcol;
            ((unsigned*)mrow)[idx] = awv;
            ((unsigned*)mrow)[144 + 2 * idx]     = bcu((f16x2){(_Float16)g0, (_Float16)g1});
            ((unsigned*)mrow)[144 + 2 * idx + 1] = bcu((f16x2){(_Float16)g2, (_Float16)g3});
        };
        f32x4 bo4 = *(const f32x4*)(bo + 4 * hq);
        setup(s_meta[2 * q],     r0, 2 * hq,     aA0[0] + bo4[0], aA0[1] + bo4[1]);
        setup(s_meta[2 * q],     r0, 2 * hq + 1, aA0[2] + bo4[2], aA0[3] + bo4[3]);
        setup(s_meta[2 * q + 1], r1, 2 * hq,     aB0[0] + bo4[0], aB0[1] + bo4[1]);
        setup(s_meta[2 * q + 1], r1, 2 * hq + 1, aB0[2] + bo4[2], aB0[3] + bo4[3]);
        if (hq == 0) {
            setup(s_meta[2 * q],     r0, 8, aA1[0] + bo[16], aA1[1] + bo[17]);
            setup(s_meta[2 * q + 1], r1, 8, aB1[0] + bo[16], aB1[1] + bo[17]);
        }
    }
    __syncthreads();                      // barrier 3

    // ---------- phase C: deformable conv, 2 independent row-chains ----------
    const _Float16* xh = xb + (pl << 3);
    const unsigned* mA = (const unsigned*)s_meta[2 * q];
    const unsigned* mB = (const unsigned*)s_meta[2 * q + 1];
    f32x4 accA[4] = {}, accB[4] = {};

    // preload address words -> registers (address path off the per-tap LDS chain)
    unsigned AWA[9], AWB[9];
    #pragma unroll
    for (int k = 0; k < 9; ++k) {
        AWA[k] = mA[k * 16 + pcol];
        AWB[k] = mB[k * 16 + pcol];
    }

    #pragma unroll
    for (int k = 0; k < 9; ++k) {
        int idx = k * 16 + pcol;
        unsigned awA = AWA[k];
        unsigned awB = AWB[k];
        u32x2 wqA = *(const u32x2*)&mA[144 + 2 * idx];
        u32x2 wqB = *(const u32x2*)&mB[144 + 2 * idx];
        unsigned sA = awA & 511u, dxA = (awA >> 9) & 1u, dyA = (awA >> 10) & 1u;
        unsigned sB = awB & 511u, dxB = (awB >> 9) & 1u, dyB = (awB >> 10) & 1u;
        u32x4 a00 = sp[sA], a01 = sp[sA + dxA];
        u32x4 a10 = sp[sA + dyA * CW], a11 = sp[sA + dyA * CW + dxA];
        u32x4 b00 = sp[sB], b01 = sp[sB + dxB];
        u32x4 b10 = sp[sB + dyB * CW], b11 = sp[sB + dyB * CW + dxB];
        if (__builtin_expect((awA & (1u << 11)) != 0u, 0)) {
            unsigned a0_ = awA >> 12;
            a00 = *(const u32x4*)(xh + (size_t)a0_ * CIN);
            a01 = *(const u32x4*)(xh + (size_t)(a0_ + dxA) * CIN);
            a10 = *(const u32x4*)(xh + (size_t)(a0_ + (dyA << 7)) * CIN);
            a11 = *(const u32x4*)(xh + (size_t)(a0_ + (dyA << 7) + dxA) * CIN);
        }
        if (__builtin_expect((awB & (1u << 11)) != 0u, 0)) {
            unsigned b0_ = awB >> 12;
            b00 = *(const u32x4*)(xh + (size_t)b0_ * CIN);
            b01 = *(const u32x4*)(xh + (size_t)(b0_ + dxB) * CIN);
            b10 = *(const u32x4*)(xh + (size_t)(b0_ + (dyB << 7)) * CIN);
            b11 = *(const u32x4*)(xh + (size_t)(b0_ + (dyB << 7) + dxB) * CIN);
        }
        f16x2 wa = bch2(wqA[0]), wc_ = bch2(wqA[1]);
        f16x2 A00 = (f16x2){wa[0], wa[0]},  A01 = (f16x2){wa[1], wa[1]};
        f16x2 A10 = (f16x2){wc_[0], wc_[0]}, A11 = (f16x2){wc_[1], wc_[1]};
        f16x2 wb_ = bch2(wqB[0]), wd_ = bch2(wqB[1]);
        f16x2 B00 = (f16x2){wb_[0], wb_[0]}, B01 = (f16x2){wb_[1], wb_[1]};
        f16x2 B10 = (f16x2){wd_[0], wd_[0]}, B11 = (f16x2){wd_[1], wd_[1]};
        u32x4 frA, frB;
        #pragma unroll
        for (int d = 0; d < 4; ++d) {
            f16x2 vA = bch2(a00[d]) * A00 + bch2(a01[d]) * A01
                     + bch2(a10[d]) * A10 + bch2(a11[d]) * A11;
            f16x2 vB = bch2(b00[d]) * B00 + bch2(b01[d]) * B01
                     + bch2(b10[d]) * B10 + bch2(b11[d]) * B11;
            frA[d] = bcu(vA);
            frB[d] = bcu(vB);
        }
        f16x8 bfA = __builtin_bit_cast(f16x8, frA);
        f16x8 bfB = __builtin_bit_cast(f16x8, frB);
        const _Float16* ab = wac2 + (size_t)(8 * k + 4 * half) * 512 + lane * 8;
        __builtin_amdgcn_s_setprio(1);
        #pragma unroll
        for (int m = 0; m < 4; ++m) {
            f16x8 wm = *(const f16x8*)(ab + m * 512);
            accA[m] = __builtin_amdgcn_mfma_f32_16x16x32_f16(wm, bfA, accA[m], 0, 0, 0);
            accB[m] = __builtin_amdgcn_mfma_f32_16x16x32_f16(wm, bfB, accB[m], 0, 0, 0);
        }
        __builtin_amdgcn_s_setprio(0);
    }

    // ---------- merged epilogue: ONE reduction round through s_x ----------
    __syncthreads();                      // barrier 4: all s_x corner reads done
    float* red = (float*)s_x;             // 16 rows x REDS cols (16.6 KB <= s_x)
    if (half == 0) {
        #pragma unroll
        for (int m = 0; m < 4; ++m)
            #pragma unroll
            for (int r2 = 0; r2 < 4; ++r2) {
                red[(m * 4 + r2) * REDS + q * 64 + lane]       = accA[m][r2];
                red[(m * 4 + r2) * REDS + 128 + q * 64 + lane] = accB[m][r2];
            }
    }
    __syncthreads();                      // barrier 5
    if (half == 1) {
        #pragma unroll
        for (int m = 0; m < 4; ++m) {
            f32x4 bc4 = *(const f32x4*)(bconv + m * 16 + (hq << 2));
            #pragma unroll
            for (int r2 = 0; r2 < 4; ++r2) {
                int co = (m << 4) + (hq << 2) + r2;
                float vA = accA[m][r2] + red[(m * 4 + r2) * REDS + q * 64 + lane] + bc4[r2];
                float vB = accB[m][r2] + red[(m * 4 + r2) * REDS + 128 + q * 64 + lane] + bc4[r2];
                out[(((size_t)b * COUT + co) * H + r0) * W + wp] = vA;
                out[(((size_t)b * COUT + co) * H + r1) * W + wp] = vB;
            }
        }
    }
}

extern "C" void kernel_launch(void* const* d_in, const int* in_sizes, int n_in,
                              void* d_out, int out_size, void* d_ws, size_t ws_size,
                              hipStream_t stream) {
    const float* x  = (const float*)d_in[0];
    const float* wo = (const float*)d_in[1];
    const float* bo = (const float*)d_in[2];
    const float* wc = (const float*)d_in[3];
    const float* bc = (const float*)d_in[4];
    float* out = (float*)d_out;

    _Float16* xt   = (_Float16*)d_ws;                                   // 16.78 MB
    _Float16* wao2 = (_Float16*)((char*)d_ws + (size_t)NB * H * W * CIN * 2);
    _Float16* wac2 = wao2 + 18432;

    x_to_nhwc<<<NB * H, 256, 0, stream>>>(x, xt);
    prep_w<<<(18432 + 36864 + 255) / 256, 256, 0, stream>>>(wo, wc, wao2, wac2);
    deform_fused<<<NB * H * W / (WR * WC), 256, 0, stream>>>(xt, wao2, wac2, bo, bc, out);
}